// Round 5
// baseline (354.606 us; speedup 1.0000x reference)
//
#include <hip/hip_runtime.h>

#define KH 18                    // harmonics
#define NPTS (128*128*128)
#define BB 4                     // batch
#define BLK 256
#define NTILES (NPTS / BLK)      // 8192
#define NBLK 512                 // 2 persistent blocks per CU (256 CUs)
#define TPB (NTILES / NBLK)      // 16 tiles per block
#define TILE_A (BLK * KH)        // 4608 floats per fourier tile (18432 B)
#define BUF_FLOATS (2 * TILE_A + BLK * 4)   // fa + fb + poly = 10240 floats (40960 B)

typedef const __attribute__((address_space(1))) void* gp1_t;
typedef __attribute__((address_space(3)))       void* lp3_t;

// Persistent 2-phase pipeline (guide §5.5 T3-lite): per tile,
// STAGE(next -> buf^1) via global_load_lds(16B) -> compute(buf) -> syncthreads.
// The sync's implicit vmcnt(0) drains next tile's DMA while this tile's compute
// already hid most of the latency; loads are ALWAYS outstanding -> no convoys.
// LDS 2 x 40960 B = 81920 B/block -> exactly 2 blocks/CU.
__global__ __launch_bounds__(BLK, 2) void dddm_kernel(
    const float* __restrict__ input_t,
    const float* __restrict__ poly,    // [N,4]
    const float* __restrict__ fa,      // [N,18]
    const float* __restrict__ fb,      // [N,18]
    const int*   __restrict__ stage_p,
    float* __restrict__ out)           // [2,B,N]: y_poly planes then y_fourier
{
    __shared__ __align__(16) float s[2 * BUF_FLOATS];   // 81920 B

    const int tid   = threadIdx.x;
    const int wv    = tid >> 6;          // wave id 0..3 (uniform per wave)
    const int lane  = tid & 63;
    const int tile0 = blockIdx.x * TPB;

    // ---- async stage of a whole tile: 40 x 1KB chunks, 10 per wave ----
    // chunk c: [0,18) fa, [18,36) fb, [36,40) poly. LDS dest is wave-uniform
    // base + lane*16 (m104) -> linear layout; global src is per-lane.
    auto stage = [&](int t, int buf) {
        const size_t f0 = (size_t)(tile0 + t) * TILE_A;       // float offset
        const float* ga = fa   + f0;
        const float* gb = fb   + f0;
        const float* gp = poly + (size_t)(tile0 + t) * (BLK * 4);
        float* lb = s + buf * BUF_FLOATS;
#pragma unroll
        for (int r = 0; r < 10; ++r) {
            const int c = wv * 10 + r;                        // wave-uniform
            const float* src;
            if (c < 18)      src = ga + c * 256        + lane * 4;
            else if (c < 36) src = gb + (c - 18) * 256 + lane * 4;
            else             src = gp + (c - 36) * 256 + lane * 4;
            __builtin_amdgcn_global_load_lds((gp1_t)src, (lp3_t)(lb + c * 256),
                                             16, 0, 0);
        }
    };

    // ---- prologue: stage tile 0; seeds overlap the DMA ----
    stage(0, 0);

    float tb[BB], c1[BB], s1[BB], dd[BB];
#pragma unroll
    for (int b = 0; b < BB; ++b) {
        const float t = input_t[b];
        tb[b] = t;
        float sn, cs;
        sincosf(6.283185307179586f * t, &sn, &cs);
        c1[b] = cs; s1[b] = sn; dd[b] = 2.0f * cs;
    }

    const int ms = *stage_p;
    const int cs_ = (ms >= 0) ? (ms < 3 ? ms : 3) : 3;
    const int kmax = (cs_ >= 3) ? 18 : (cs_ == 2 ? 9 : (cs_ == 1 ? 3 : 0));

    __syncthreads();                                 // buf0 ready

    for (int t = 0; t < TPB; ++t) {
        if (t + 1 < TPB) stage(t + 1, (t + 1) & 1);  // issue-early, next buffer

        const float* sb = s + (t & 1) * BUF_FLOATS;

        // poly: staged float4 row + Horner
        const float4 c4 = reinterpret_cast<const float4*>(sb + 2 * TILE_A)[tid];
        float yp[BB], yf[BB], cc[BB], ss[BB], cp[BB], sp[BB];
#pragma unroll
        for (int b = 0; b < BB; ++b) {
            const float t0 = tb[b];
            yp[b] = ((c4.w * t0 + c4.z) * t0 + c4.y) * t0 + c4.x;
            cc[b] = c1[b]; ss[b] = s1[b];            // k = 1
            cp[b] = 1.0f;  sp[b] = 0.0f;             // k = 0
            yf[b] = 0.0f;
        }

        // fourier: fused cos+sin Chebyshev recurrence, float2 LDS reads
        const float2* ar = reinterpret_cast<const float2*>(sb + tid * KH);
        const float2* br = reinterpret_cast<const float2*>(sb + TILE_A + tid * KH);

        if (kmax == KH) {
#pragma unroll
            for (int j = 0; j < 9; ++j) {
                const float2 a2 = ar[j];
                const float2 b2 = br[j];
#pragma unroll
                for (int u = 0; u < 2; ++u) {
                    const float ak = u ? a2.y : a2.x;
                    const float bk = u ? b2.y : b2.x;
#pragma unroll
                    for (int b = 0; b < BB; ++b) {
                        yf[b] = __builtin_fmaf(ak, cc[b], yf[b]);
                        yf[b] = __builtin_fmaf(bk, ss[b], yf[b]);
                        const float cn = __builtin_fmaf(dd[b], cc[b], -cp[b]);
                        const float sn = __builtin_fmaf(dd[b], ss[b], -sp[b]);
                        cp[b] = cc[b]; cc[b] = cn;
                        sp[b] = ss[b]; ss[b] = sn;
                    }
                }
            }
        } else if (kmax > 0) {
            for (int k = 0; k < kmax; ++k) {
                const float ak = sb[tid * KH + k];
                const float bk = sb[TILE_A + tid * KH + k];
#pragma unroll
                for (int b = 0; b < BB; ++b) {
                    yf[b] = __builtin_fmaf(ak, cc[b], yf[b]);
                    yf[b] = __builtin_fmaf(bk, ss[b], yf[b]);
                    const float cn = __builtin_fmaf(dd[b], cc[b], -cp[b]);
                    const float sn = __builtin_fmaf(dd[b], ss[b], -sp[b]);
                    cp[b] = cc[b]; cc[b] = cn;
                    sp[b] = ss[b]; ss[b] = sn;
                }
            }
        }

        // coalesced dword stores per (output, b) plane
        const int n = (tile0 + t) * BLK + tid;
#pragma unroll
        for (int b = 0; b < BB; ++b) {
            out[(size_t)b * NPTS + n]        = yp[b];
            out[(size_t)(BB + b) * NPTS + n] = yf[b];
        }

        // single barrier per tile: implicit vmcnt(0) drains stage(t+1) DMA
        // (buf^1 ready) AND all reads of buf finished before it's re-staged.
        __syncthreads();
    }
}

extern "C" void kernel_launch(void* const* d_in, const int* in_sizes, int n_in,
                              void* d_out, int out_size, void* d_ws, size_t ws_size,
                              hipStream_t stream) {
    const float* input_t = (const float*)d_in[0];
    const float* poly    = (const float*)d_in[1];
    const float* fa      = (const float*)d_in[2];
    const float* fb      = (const float*)d_in[3];
    const int*   stage   = (const int*)d_in[4];
    float* out = (float*)d_out;

    dddm_kernel<<<NBLK, BLK, 0, stream>>>(input_t, poly, fa, fb, stage, out);
}